// Round 4
// baseline (416.072 us; speedup 1.0000x reference)
//
#include <hip/hip_runtime.h>
#include <hip/hip_bf16.h>

#define D_MODEL 768
#define NSEQ    8192
#define NBATCH  4
#define MROWS   (NBATCH*NSEQ)   // 32768
#define CHUNK   128
#define NCHUNK  (NSEQ/CHUNK)    // 64

// GEMM tile: BM=128, BN=128, BK=64, 4 waves 2x2, wave tile 64x64, acc 2x2 (64 AGPR)
#define BM 128
#define BN 128
#define BK 64

typedef __attribute__((ext_vector_type(8)))  short bshort8;
typedef __attribute__((ext_vector_type(16))) float f32x16;

__device__ __forceinline__ float bf2f(ushort u){
  union { unsigned int i; float f; } x; x.i = ((unsigned int)u) << 16; return x.f;
}
__device__ __forceinline__ ushort f2bf(float f){
  union { float f; unsigned int i; } x; x.f = f;
  unsigned int r = x.i + 0x7fffu + ((x.i >> 16) & 1u);
  return (ushort)(r >> 16);
}
__device__ __forceinline__ float silu_f(float v){ return v / (1.0f + __expf(-v)); }

__device__ __forceinline__ void async_copy16(const ushort* g, ushort* l){
  __builtin_amdgcn_global_load_lds((const __attribute__((address_space(1))) void*)g,
                                   (__attribute__((address_space(3))) void*)l, 16, 0, 0);
}

// ---------------- weight transpose + bf16 convert: in[R][C] f32 -> out[C][R] bf16
__global__ void tr_cvt(const float* __restrict__ in, ushort* __restrict__ out, int R, int C){
  __shared__ float tile[32][33];
  int c0 = blockIdx.x*32, r0 = blockIdx.y*32;
  int tx = threadIdx.x & 31, ty = threadIdx.x >> 5;
  #pragma unroll
  for (int p=0;p<4;p++){
    int r = ty + p*8;
    tile[r][tx] = in[(size_t)(r0+r)*C + c0 + tx];
  }
  __syncthreads();
  #pragma unroll
  for (int p=0;p<4;p++){
    int c = ty + p*8;
    out[(size_t)(c0+c)*R + r0 + tx] = f2bf(tile[tx][c]);
  }
}

// ---------------- x fp32 -> bf16, 8 elems/thread, 16B stores
__global__ void cvt_bf16(const float* __restrict__ in, ushort* __restrict__ out, int n){
  int i = (blockIdx.x*256 + threadIdx.x)*8;
  if (i >= n) return;
  const float4 f0 = *(const float4*)(in + i);
  const float4 f1 = *(const float4*)(in + i + 4);
  ushort o[8];
  o[0]=f2bf(f0.x); o[1]=f2bf(f0.y); o[2]=f2bf(f0.z); o[3]=f2bf(f0.w);
  o[4]=f2bf(f1.x); o[5]=f2bf(f1.y); o[6]=f2bf(f1.z); o[7]=f2bf(f1.w);
  *(ulonglong2*)(out + i) = *(const ulonglong2*)o;
}

// ---------------- GEMM1: 128x128 tile, BK=64, 32x32x16 MFMA, swizzled LDS.
// Round-4 changes vs round-3 (which benched 110us, Occ 37%, MfmaUtil 31%):
//  (a) grid order swapped: blockIdx.x = bn (12 cols), blockIdx.y = bm. The
//      ~768 co-resident blocks now span ~64 bm panels x 12 bn, so each 196KB
//      A-panel is fetched from HBM once and served 12x from L2/L3 (round-3
//      order streamed all of A once per bn pass: FETCH 204MB ~= 4x A).
//  (b) __launch_bounds__(256,4): combined regs 60 VGPR + 64 AGPR = 124 <= 128,
//      LDS 32KB x4 = 128KB <= 160KB -> 4 waves/SIMD (was capped at 3 by (256,3)).
// Schedule itself unchanged (proven simple 2-barrier loop).
// A[M][K] bf16 row-major, BT[N][K] bf16 row-major.
// LDS: physical 16B slot p holds logical (row r=p>>3, chunk (p&7)^(r&7)).
// N=1536 in 12 col-blocks: bn<6 -> xc bf16; bn>=6 -> silu -> z bf16
__global__ __launch_bounds__(256,4) void gemm1_bt(
    const ushort* __restrict__ A, const ushort* __restrict__ BT,
    ushort* __restrict__ oxc, ushort* __restrict__ oz, int K)
{
  __shared__ __align__(16) ushort Asm[BM*BK];   // 16 KB
  __shared__ __align__(16) ushort Bsm[BN*BK];   // 16 KB
  const int tid = threadIdx.x;
  const int bn = blockIdx.x, bm = blockIdx.y;   // bn fastest -> A-panel L2 reuse
  const int lane = tid & 63, wid = tid >> 6;
  const int wm = (wid >> 1) * 64, wn = (wid & 1) * 64;
  const int l31 = lane & 31, half = lane >> 5;

  const ushort* Ag[4]; ushort* Al[4];
  #pragma unroll
  for (int it=0; it<4; ++it){
    int p  = it*256 + tid;
    int r  = p >> 3;
    int cl = (p & 7) ^ (r & 7);
    Ag[it] = A + (size_t)(bm*BM + r)*K + cl*8;
    Al[it] = Asm + p*8;
  }
  const ushort* Bg[4]; ushort* Bl[4];
  #pragma unroll
  for (int it=0; it<4; ++it){
    int p  = it*256 + tid;
    int r  = p >> 3;
    int cl = (p & 7) ^ (r & 7);
    Bg[it] = BT + (size_t)(bn*BN + r)*K + cl*8;
    Bl[it] = Bsm + p*8;
  }

  int arow[2], ar7[2], brow[2], br7[2];
  #pragma unroll
  for (int i=0;i<2;i++){
    int ra = wm + i*32 + l31; arow[i] = ra*BK; ar7[i] = ra & 7;
  }
  #pragma unroll
  for (int j=0;j<2;j++){
    int rb = wn + j*32 + l31; brow[j] = rb*BK; br7[j] = rb & 7;
  }

  f32x16 acc[2][2];
  #pragma unroll
  for (int i=0;i<2;i++)
    #pragma unroll
    for (int j=0;j<2;j++)
      #pragma unroll
      for (int r=0;r<16;r++) acc[i][j][r] = 0.f;

  const int KT = K / BK;  // 12
  for (int kt=0; kt<KT; ++kt){
    __syncthreads();
    #pragma unroll
    for (int it=0; it<4; ++it){ async_copy16(Ag[it], Al[it]); Ag[it] += BK; }
    #pragma unroll
    for (int it=0; it<4; ++it){ async_copy16(Bg[it], Bl[it]); Bg[it] += BK; }
    asm volatile("s_waitcnt vmcnt(0)" ::: "memory");
    __syncthreads();

    #pragma unroll
    for (int s=0; s<4; ++s){
      const int c = s*2 + half;
      bshort8 av[2], bv[2];
      #pragma unroll
      for (int i=0;i<2;i++)
        av[i] = *(const bshort8*)(Asm + arow[i] + ((c ^ ar7[i]) << 3));
      #pragma unroll
      for (int j=0;j<2;j++)
        bv[j] = *(const bshort8*)(Bsm + brow[j] + ((c ^ br7[j]) << 3));
      #pragma unroll
      for (int i=0;i<2;i++)
        #pragma unroll
        for (int j=0;j<2;j++)
          acc[i][j] = __builtin_amdgcn_mfma_f32_32x32x16_bf16(av[i], bv[j], acc[i][j], 0,0,0);
    }
  }

  // epilogue: C/D 32x32: col=lane&31, row=(reg&3)+8*(reg>>2)+4*(lane>>5)
  if (bn < 6){
    #pragma unroll
    for (int i=0;i<2;i++){
      const int Rbase = bm*BM + wm + i*32 + 4*half;
      #pragma unroll
      for (int j=0;j<2;j++){
        const int Cc = bn*BN + wn + j*32 + l31;
        #pragma unroll
        for (int reg=0; reg<16; reg++){
          const int R = Rbase + (reg & 3) + 8*(reg >> 2);
          oxc[(size_t)R*768 + Cc] = f2bf(acc[i][j][reg]);
        }
      }
    }
  } else {
    #pragma unroll
    for (int i=0;i<2;i++){
      const int Rbase = bm*BM + wm + i*32 + 4*half;
      #pragma unroll
      for (int j=0;j<2;j++){
        const int Cc = bn*BN - 768 + wn + j*32 + l31;
        #pragma unroll
        for (int reg=0; reg<16; reg++){
          const int R = Rbase + (reg & 3) + 8*(reg >> 2);
          oz[(size_t)R*768 + Cc] = f2bf(silu_f(acc[i][j][reg]));
        }
      }
    }
  }
}

// ---------------- GEMM2: same 128x128 shape, fp32 out. Grid (6, 256), bn fastest.
__global__ __launch_bounds__(256,4) void gemm2_bt(
    const ushort* __restrict__ A, const ushort* __restrict__ BT,
    float* __restrict__ of, int K)
{
  __shared__ __align__(16) ushort Asm[BM*BK];   // 16 KB
  __shared__ __align__(16) ushort Bsm[BN*BK];   // 16 KB
  const int tid = threadIdx.x;
  const int bn = blockIdx.x, bm = blockIdx.y;   // bn fastest -> A-panel L2 reuse
  const int lane = tid & 63, wid = tid >> 6;
  const int wm = (wid >> 1) * 64, wn = (wid & 1) * 64;
  const int l31 = lane & 31, half = lane >> 5;

  const ushort* Ag[4]; ushort* Al[4];
  #pragma unroll
  for (int it=0; it<4; ++it){
    int p  = it*256 + tid;
    int r  = p >> 3;
    int cl = (p & 7) ^ (r & 7);
    Ag[it] = A + (size_t)(bm*BM + r)*K + cl*8;
    Al[it] = Asm + p*8;
  }
  const ushort* Bg[4]; ushort* Bl[4];
  #pragma unroll
  for (int it=0; it<4; ++it){
    int p  = it*256 + tid;
    int r  = p >> 3;
    int cl = (p & 7) ^ (r & 7);
    Bg[it] = BT + (size_t)(bn*BN + r)*K + cl*8;
    Bl[it] = Bsm + p*8;
  }

  int arow[2], ar7[2], brow[2], br7[2];
  #pragma unroll
  for (int i=0;i<2;i++){
    int ra = wm + i*32 + l31; arow[i] = ra*BK; ar7[i] = ra & 7;
  }
  #pragma unroll
  for (int j=0;j<2;j++){
    int rb = wn + j*32 + l31; brow[j] = rb*BK; br7[j] = rb & 7;
  }

  f32x16 acc[2][2];
  #pragma unroll
  for (int i=0;i<2;i++)
    #pragma unroll
    for (int j=0;j<2;j++)
      #pragma unroll
      for (int r=0;r<16;r++) acc[i][j][r] = 0.f;

  const int KT = K / BK;  // 12
  for (int kt=0; kt<KT; ++kt){
    __syncthreads();
    #pragma unroll
    for (int it=0; it<4; ++it){ async_copy16(Ag[it], Al[it]); Ag[it] += BK; }
    #pragma unroll
    for (int it=0; it<4; ++it){ async_copy16(Bg[it], Bl[it]); Bg[it] += BK; }
    asm volatile("s_waitcnt vmcnt(0)" ::: "memory");
    __syncthreads();

    #pragma unroll
    for (int s=0; s<4; ++s){
      const int c = s*2 + half;
      bshort8 av[2], bv[2];
      #pragma unroll
      for (int i=0;i<2;i++)
        av[i] = *(const bshort8*)(Asm + arow[i] + ((c ^ ar7[i]) << 3));
      #pragma unroll
      for (int j=0;j<2;j++)
        bv[j] = *(const bshort8*)(Bsm + brow[j] + ((c ^ br7[j]) << 3));
      #pragma unroll
      for (int i=0;i<2;i++)
        #pragma unroll
        for (int j=0;j<2;j++)
          acc[i][j] = __builtin_amdgcn_mfma_f32_32x32x16_bf16(av[i], bv[j], acc[i][j], 0,0,0);
    }
  }

  #pragma unroll
  for (int i=0;i<2;i++){
    const int Rbase = bm*BM + wm + i*32 + 4*half;
    #pragma unroll
    for (int j=0;j<2;j++){
      const int Cc = bn*BN + wn + j*32 + l31;
      #pragma unroll
      for (int reg=0; reg<16; reg++){
        const int R = Rbase + (reg & 3) + 8*(reg >> 2);
        of[(size_t)R*768 + Cc] = acc[i][j][reg];
      }
    }
  }
}

// ---------------- pass 1: conv+silu, per-chunk sums; 2 channels/thread, ushort2 loads
__global__ void conv_psum(const ushort* __restrict__ xc, const float* __restrict__ cw,
                          const float* __restrict__ cb, float* __restrict__ psum){
  int c0 = threadIdx.x * 2;               // 0..766
  int b = blockIdx.z, ch = blockIdx.x;
  int t0 = ch*CHUNK;
  const ushort* xp = xc + (size_t)b*NSEQ*768 + c0;
  float w0a=cw[c0*3+0], w1a=cw[c0*3+1], w2a=cw[c0*3+2], ba=cb[c0];
  float w0b=cw[c0*3+3], w1b=cw[c0*3+4], w2b=cw[c0*3+5], bb=cb[c0+1];
  float am2=0.f, am1=0.f, bm2=0.f, bm1=0.f;
  if (t0>=2){ ushort2 u = *(const ushort2*)(xp + (size_t)(t0-2)*768); am2=bf2f(u.x); bm2=bf2f(u.y); }
  if (t0>=1){ ushort2 u = *(const ushort2*)(xp + (size_t)(t0-1)*768); am1=bf2f(u.x); bm1=bf2f(u.y); }
  float sa=0.f, sb=0.f;
  #pragma unroll 4
  for (int i=0;i<CHUNK;i++){
    ushort2 u = *(const ushort2*)(xp + (size_t)(t0+i)*768);
    float xa = bf2f(u.x), xb = bf2f(u.y);
    sa += silu_f(w0a*am2 + w1a*am1 + w2a*xa + ba);
    sb += silu_f(w0b*bm2 + w1b*bm1 + w2b*xb + bb);
    am2=am1; am1=xa; bm2=bm1; bm1=xb;
  }
  float2* pp = (float2*)(psum + ((size_t)b*NCHUNK + ch)*768 + c0);
  *pp = make_float2(sa, sb);
}

// ---------------- pass 2: exclusive scan of chunk sums per (b,c)
__global__ void scan_chunks(const float* __restrict__ psum, float* __restrict__ offs){
  int idx = blockIdx.x*256 + threadIdx.x; // 0..3071
  int b = idx/768, c = idx%768;
  float run = 0.f;
  for (int ch=0; ch<NCHUNK; ch++){
    size_t o = ((size_t)b*NCHUNK + ch)*768 + c;
    offs[o] = run;
    run += psum[o];
  }
}

// ---------------- pass 3: replay conv+silu, apply SSM + gate -> v bf16; 2 ch/thread
__global__ void scan_apply(const ushort* __restrict__ xc, const ushort* __restrict__ zb,
                           const float* __restrict__ cw, const float* __restrict__ cb,
                           const float* __restrict__ Bm, const float* __restrict__ Cm,
                           const float* __restrict__ Dv, const float* __restrict__ offs,
                           ushort* __restrict__ v){
  int c0 = threadIdx.x * 2;
  int b = blockIdx.z, ch = blockIdx.x;
  int t0 = ch*CHUNK;
  size_t base = (size_t)b*NSEQ*768 + c0;
  const ushort* xp = xc + base;
  const ushort* zp = zb + base;
  ushort* vp = v + base;
  float w0a=cw[c0*3+0], w1a=cw[c0*3+1], w2a=cw[c0*3+2], ba=cb[c0];
  float w0b=cw[c0*3+3], w1b=cw[c0*3+4], w2b=cw[c0*3+5], bb=cb[c0+1];
  float bca=0.f, bcb=0.f;
  #pragma unroll
  for (int s=0;s<8;s++){ bca += Bm[c0*8+s]*Cm[c0*8+s]; bcb += Bm[c0*8+8+s]*Cm[c0*8+8+s]; }
  float dda = Dv[c0], ddb = Dv[c0+1];
  const float2 off2 = *(const float2*)(offs + ((size_t)b*NCHUNK + ch)*768 + c0);
  float cua = off2.x, cub = off2.y;
  float am2=0.f, am1=0.f, bm2=0.f, bm1=0.f;
  if (t0>=2){ ushort2 u = *(const ushort2*)(xp + (size_t)(t0-2)*768); am2=bf2f(u.x); bm2=bf2f(u.y); }
  if (t0>=1){ ushort2 u = *(const ushort2*)(xp + (size_t)(t0-1)*768); am1=bf2f(u.x); bm1=bf2f(u.y); }
  #pragma unroll 4
  for (int i=0;i<CHUNK;i++){
    size_t o = (size_t)(t0+i)*768;
    ushort2 u = *(const ushort2*)(xp + o);
    ushort2 z2 = *(const ushort2*)(zp + o);
    float xa = bf2f(u.x), xb = bf2f(u.y);
    float ua = silu_f(w0a*am2 + w1a*am1 + w2a*xa + ba);
    float ub = silu_f(w0b*bm2 + w1b*bm1 + w2b*xb + bb);
    cua += ua; cub += ub;
    float ya = bca*cua + dda*ua;
    float yb = bcb*cub + ddb*ub;
    ushort2 o2; o2.x = f2bf(ya * bf2f(z2.x)); o2.y = f2bf(yb * bf2f(z2.y));
    *(ushort2*)(vp + o) = o2;
    am2=am1; am1=xa; bm2=bm1; bm1=xb;
  }
}

extern "C" void kernel_launch(void* const* d_in, const int* in_sizes, int n_in,
                              void* d_out, int out_size, void* d_ws, size_t ws_size,
                              hipStream_t stream)
{
  const float* x      = (const float*)d_in[0];
  const float* W_in   = (const float*)d_in[1];
  const float* conv_w = (const float*)d_in[2];
  const float* conv_b = (const float*)d_in[3];
  const float* Bm     = (const float*)d_in[4];
  const float* Cm     = (const float*)d_in[5];
  const float* Dv     = (const float*)d_in[6];
  const float* W_out  = (const float*)d_in[7];
  float* out = (float*)d_out;

  char* ws = (char*)d_ws;
  ushort* xbf   = (ushort*)(ws + 0);          // 50331648; reused as v after GEMM1
  ushort* xcbf  = (ushort*)(ws + 50331648);   // 50331648
  ushort* zbf   = (ushort*)(ws + 100663296);  // 50331648
  ushort* wint  = (ushort*)(ws + 150994944);  // 2359296
  ushort* woutt = (ushort*)(ws + 153354240);  // 1179648
  float*  psum  = (float*)(ws + 154533888);   // 786432
  float*  offs  = (float*)(ws + 155320320);   // 786432
  if (ws_size < 156106752) return;

  tr_cvt<<<dim3(1536/32, 768/32), 256, 0, stream>>>(W_in,  wint,  768, 1536);
  tr_cvt<<<dim3(768/32,  768/32), 256, 0, stream>>>(W_out, woutt, 768, 768);
  cvt_bf16<<<(MROWS*768)/2048, 256, 0, stream>>>(x, xbf, MROWS*768);

  // bn fastest (blockIdx.x), bm slow (blockIdx.y): A-panel reuse in L2/L3
  gemm1_bt<<<dim3(1536/BN, MROWS/BM), 256, 0, stream>>>(xbf, wint, xcbf, zbf, 768);

  conv_psum  <<<dim3(NCHUNK, 1, NBATCH), 384, 0, stream>>>(xcbf, conv_w, conv_b, psum);
  scan_chunks<<<12, 256, 0, stream>>>(psum, offs);
  scan_apply <<<dim3(NCHUNK, 1, NBATCH), 384, 0, stream>>>(xcbf, zbf, conv_w, conv_b,
                                                           Bm, Cm, Dv, offs, xbf /*v*/);

  gemm2_bt<<<dim3(768/BN, MROWS/BM), 256, 0, stream>>>(xbf, woutt, out, 768);
}

// Round 5
// 390.899 us; speedup vs baseline: 1.0644x; 1.0644x over previous
//
#include <hip/hip_runtime.h>
#include <hip/hip_bf16.h>

#define D_MODEL 768
#define NSEQ    8192
#define NBATCH  4
#define MROWS   (NBATCH*NSEQ)   // 32768
#define CHUNK   64
#define NCHUNK  (NSEQ/CHUNK)    // 128

// GEMM tile: BM=128, BN=128, BK=64, 4 waves 2x2, wave tile 64x64, acc 2x2 (64 AGPR)
#define BM 128
#define BN 128
#define BK 64

typedef __attribute__((ext_vector_type(8)))  short bshort8;
typedef __attribute__((ext_vector_type(16))) float f32x16;

__device__ __forceinline__ float bf2f(ushort u){
  union { unsigned int i; float f; } x; x.i = ((unsigned int)u) << 16; return x.f;
}
__device__ __forceinline__ ushort f2bf(float f){
  union { float f; unsigned int i; } x; x.f = f;
  unsigned int r = x.i + 0x7fffu + ((x.i >> 16) & 1u);
  return (ushort)(r >> 16);
}
__device__ __forceinline__ float silu_f(float v){ return v / (1.0f + __expf(-v)); }

__device__ __forceinline__ void async_copy16(const ushort* g, ushort* l){
  __builtin_amdgcn_global_load_lds((const __attribute__((address_space(1))) void*)g,
                                   (__attribute__((address_space(3))) void*)l, 16, 0, 0);
}

// ---------------- weight transpose + bf16 convert: in[R][C] f32 -> out[C][R] bf16
__global__ void tr_cvt(const float* __restrict__ in, ushort* __restrict__ out, int R, int C){
  __shared__ float tile[32][33];
  int c0 = blockIdx.x*32, r0 = blockIdx.y*32;
  int tx = threadIdx.x & 31, ty = threadIdx.x >> 5;
  #pragma unroll
  for (int p=0;p<4;p++){
    int r = ty + p*8;
    tile[r][tx] = in[(size_t)(r0+r)*C + c0 + tx];
  }
  __syncthreads();
  #pragma unroll
  for (int p=0;p<4;p++){
    int c = ty + p*8;
    out[(size_t)(c0+c)*R + r0 + tx] = f2bf(tile[tx][c]);
  }
}

// ---------------- x fp32 -> bf16, 8 elems/thread, 16B stores
__global__ void cvt_bf16(const float* __restrict__ in, ushort* __restrict__ out, int n){
  int i = (blockIdx.x*256 + threadIdx.x)*8;
  if (i >= n) return;
  const float4 f0 = *(const float4*)(in + i);
  const float4 f1 = *(const float4*)(in + i + 4);
  ushort o[8];
  o[0]=f2bf(f0.x); o[1]=f2bf(f0.y); o[2]=f2bf(f0.z); o[3]=f2bf(f0.w);
  o[4]=f2bf(f1.x); o[5]=f2bf(f1.y); o[6]=f2bf(f1.z); o[7]=f2bf(f1.w);
  *(ulonglong2*)(out + i) = *(const ulonglong2*)o;
}

// ---------------- GEMM1: 128x128 tile, BK=64, 32x32x16 MFMA, swizzled LDS.
// Round-3 proven config (best measured): 2x2 f32x16 acc = 64 AGPR, launch
// bounds (256,3) -> 3 blocks/CU, simple 2-barrier schedule, bm-fastest grid.
// (Round-4's grid swap + (256,4) were both null/regressive -> reverted.)
// A[M][K] bf16 row-major, BT[N][K] bf16 row-major.
// LDS: physical 16B slot p holds logical (row r=p>>3, chunk (p&7)^(r&7)).
// N=1536 in 12 col-blocks: bn<6 -> xc bf16; bn>=6 -> silu -> z bf16
__global__ __launch_bounds__(256,3) void gemm1_bt(
    const ushort* __restrict__ A, const ushort* __restrict__ BT,
    ushort* __restrict__ oxc, ushort* __restrict__ oz, int K)
{
  __shared__ __align__(16) ushort Asm[BM*BK];   // 16 KB
  __shared__ __align__(16) ushort Bsm[BN*BK];   // 16 KB
  const int tid = threadIdx.x;
  const int bm = blockIdx.x, bn = blockIdx.y;
  const int lane = tid & 63, wid = tid >> 6;
  const int wm = (wid >> 1) * 64, wn = (wid & 1) * 64;
  const int l31 = lane & 31, half = lane >> 5;

  const ushort* Ag[4]; ushort* Al[4];
  #pragma unroll
  for (int it=0; it<4; ++it){
    int p  = it*256 + tid;
    int r  = p >> 3;
    int cl = (p & 7) ^ (r & 7);
    Ag[it] = A + (size_t)(bm*BM + r)*K + cl*8;
    Al[it] = Asm + p*8;
  }
  const ushort* Bg[4]; ushort* Bl[4];
  #pragma unroll
  for (int it=0; it<4; ++it){
    int p  = it*256 + tid;
    int r  = p >> 3;
    int cl = (p & 7) ^ (r & 7);
    Bg[it] = BT + (size_t)(bn*BN + r)*K + cl*8;
    Bl[it] = Bsm + p*8;
  }

  int arow[2], ar7[2], brow[2], br7[2];
  #pragma unroll
  for (int i=0;i<2;i++){
    int ra = wm + i*32 + l31; arow[i] = ra*BK; ar7[i] = ra & 7;
  }
  #pragma unroll
  for (int j=0;j<2;j++){
    int rb = wn + j*32 + l31; brow[j] = rb*BK; br7[j] = rb & 7;
  }

  f32x16 acc[2][2];
  #pragma unroll
  for (int i=0;i<2;i++)
    #pragma unroll
    for (int j=0;j<2;j++)
      #pragma unroll
      for (int r=0;r<16;r++) acc[i][j][r] = 0.f;

  const int KT = K / BK;  // 12
  for (int kt=0; kt<KT; ++kt){
    __syncthreads();
    #pragma unroll
    for (int it=0; it<4; ++it){ async_copy16(Ag[it], Al[it]); Ag[it] += BK; }
    #pragma unroll
    for (int it=0; it<4; ++it){ async_copy16(Bg[it], Bl[it]); Bg[it] += BK; }
    asm volatile("s_waitcnt vmcnt(0)" ::: "memory");
    __syncthreads();

    #pragma unroll
    for (int s=0; s<4; ++s){
      const int c = s*2 + half;
      bshort8 av[2], bv[2];
      #pragma unroll
      for (int i=0;i<2;i++)
        av[i] = *(const bshort8*)(Asm + arow[i] + ((c ^ ar7[i]) << 3));
      #pragma unroll
      for (int j=0;j<2;j++)
        bv[j] = *(const bshort8*)(Bsm + brow[j] + ((c ^ br7[j]) << 3));
      #pragma unroll
      for (int i=0;i<2;i++)
        #pragma unroll
        for (int j=0;j<2;j++)
          acc[i][j] = __builtin_amdgcn_mfma_f32_32x32x16_bf16(av[i], bv[j], acc[i][j], 0,0,0);
    }
  }

  // epilogue: C/D 32x32: col=lane&31, row=(reg&3)+8*(reg>>2)+4*(lane>>5)
  if (bn < 6){
    #pragma unroll
    for (int i=0;i<2;i++){
      const int Rbase = bm*BM + wm + i*32 + 4*half;
      #pragma unroll
      for (int j=0;j<2;j++){
        const int Cc = bn*BN + wn + j*32 + l31;
        #pragma unroll
        for (int reg=0; reg<16; reg++){
          const int R = Rbase + (reg & 3) + 8*(reg >> 2);
          oxc[(size_t)R*768 + Cc] = f2bf(acc[i][j][reg]);
        }
      }
    }
  } else {
    #pragma unroll
    for (int i=0;i<2;i++){
      const int Rbase = bm*BM + wm + i*32 + 4*half;
      #pragma unroll
      for (int j=0;j<2;j++){
        const int Cc = bn*BN - 768 + wn + j*32 + l31;
        #pragma unroll
        for (int reg=0; reg<16; reg++){
          const int R = Rbase + (reg & 3) + 8*(reg >> 2);
          oz[(size_t)R*768 + Cc] = f2bf(silu_f(acc[i][j][reg]));
        }
      }
    }
  }
}

// ---------------- GEMM2: same 128x128 shape, fp32 out. Grid (256, 6), bm fastest.
__global__ __launch_bounds__(256,3) void gemm2_bt(
    const ushort* __restrict__ A, const ushort* __restrict__ BT,
    float* __restrict__ of, int K)
{
  __shared__ __align__(16) ushort Asm[BM*BK];   // 16 KB
  __shared__ __align__(16) ushort Bsm[BN*BK];   // 16 KB
  const int tid = threadIdx.x;
  const int bm = blockIdx.x, bn = blockIdx.y;
  const int lane = tid & 63, wid = tid >> 6;
  const int wm = (wid >> 1) * 64, wn = (wid & 1) * 64;
  const int l31 = lane & 31, half = lane >> 5;

  const ushort* Ag[4]; ushort* Al[4];
  #pragma unroll
  for (int it=0; it<4; ++it){
    int p  = it*256 + tid;
    int r  = p >> 3;
    int cl = (p & 7) ^ (r & 7);
    Ag[it] = A + (size_t)(bm*BM + r)*K + cl*8;
    Al[it] = Asm + p*8;
  }
  const ushort* Bg[4]; ushort* Bl[4];
  #pragma unroll
  for (int it=0; it<4; ++it){
    int p  = it*256 + tid;
    int r  = p >> 3;
    int cl = (p & 7) ^ (r & 7);
    Bg[it] = BT + (size_t)(bn*BN + r)*K + cl*8;
    Bl[it] = Bsm + p*8;
  }

  int arow[2], ar7[2], brow[2], br7[2];
  #pragma unroll
  for (int i=0;i<2;i++){
    int ra = wm + i*32 + l31; arow[i] = ra*BK; ar7[i] = ra & 7;
  }
  #pragma unroll
  for (int j=0;j<2;j++){
    int rb = wn + j*32 + l31; brow[j] = rb*BK; br7[j] = rb & 7;
  }

  f32x16 acc[2][2];
  #pragma unroll
  for (int i=0;i<2;i++)
    #pragma unroll
    for (int j=0;j<2;j++)
      #pragma unroll
      for (int r=0;r<16;r++) acc[i][j][r] = 0.f;

  const int KT = K / BK;  // 12
  for (int kt=0; kt<KT; ++kt){
    __syncthreads();
    #pragma unroll
    for (int it=0; it<4; ++it){ async_copy16(Ag[it], Al[it]); Ag[it] += BK; }
    #pragma unroll
    for (int it=0; it<4; ++it){ async_copy16(Bg[it], Bl[it]); Bg[it] += BK; }
    asm volatile("s_waitcnt vmcnt(0)" ::: "memory");
    __syncthreads();

    #pragma unroll
    for (int s=0; s<4; ++s){
      const int c = s*2 + half;
      bshort8 av[2], bv[2];
      #pragma unroll
      for (int i=0;i<2;i++)
        av[i] = *(const bshort8*)(Asm + arow[i] + ((c ^ ar7[i]) << 3));
      #pragma unroll
      for (int j=0;j<2;j++)
        bv[j] = *(const bshort8*)(Bsm + brow[j] + ((c ^ br7[j]) << 3));
      #pragma unroll
      for (int i=0;i<2;i++)
        #pragma unroll
        for (int j=0;j<2;j++)
          acc[i][j] = __builtin_amdgcn_mfma_f32_32x32x16_bf16(av[i], bv[j], acc[i][j], 0,0,0);
    }
  }

  #pragma unroll
  for (int i=0;i<2;i++){
    const int Rbase = bm*BM + wm + i*32 + 4*half;
    #pragma unroll
    for (int j=0;j<2;j++){
      const int Cc = bn*BN + wn + j*32 + l31;
      #pragma unroll
      for (int reg=0; reg<16; reg++){
        const int R = Rbase + (reg & 3) + 8*(reg >> 2);
        of[(size_t)R*768 + Cc] = acc[i][j][reg];
      }
    }
  }
}

// ---------------- pass 1: conv+silu, per-chunk sums.
// Round-5: CHUNK 128->64 and ONE channel/thread (768-thread blocks).
// Total threads 98K->393K = 6 waves/SIMD (was 1.5) -> latency-bound serial
// loop now hidden by TLP. A wave reads 64 consecutive ushorts = 128B/step,
// adjacent waves cover adjacent 128B of the same row (L1/L2 friendly).
__global__ void conv_psum(const ushort* __restrict__ xc, const float* __restrict__ cw,
                          const float* __restrict__ cb, float* __restrict__ psum){
  int c = threadIdx.x;                    // 0..767
  int b = blockIdx.z, ch = blockIdx.x;
  int t0 = ch*CHUNK;
  const ushort* xp = xc + (size_t)b*NSEQ*768 + c;
  float w0=cw[c*3+0], w1=cw[c*3+1], w2=cw[c*3+2], bia=cb[c];
  float m2=0.f, m1=0.f;
  if (t0>=2) m2 = bf2f(xp[(size_t)(t0-2)*768]);
  if (t0>=1) m1 = bf2f(xp[(size_t)(t0-1)*768]);
  float s=0.f;
  #pragma unroll 4
  for (int i=0;i<CHUNK;i++){
    float x = bf2f(xp[(size_t)(t0+i)*768]);
    s += silu_f(w0*m2 + w1*m1 + w2*x + bia);
    m2=m1; m1=x;
  }
  psum[((size_t)b*NCHUNK + ch)*768 + c] = s;
}

// ---------------- pass 2: exclusive scan of chunk sums per (b,c); 128 chunks now
__global__ void scan_chunks(const float* __restrict__ psum, float* __restrict__ offs){
  int idx = blockIdx.x*256 + threadIdx.x; // 0..3071
  int b = idx/768, c = idx%768;
  float run = 0.f;
  #pragma unroll 8
  for (int ch=0; ch<NCHUNK; ch++){
    size_t o = ((size_t)b*NCHUNK + ch)*768 + c;
    offs[o] = run;
    run += psum[o];
  }
}

// ---------------- pass 3: replay conv+silu, apply SSM + gate -> v bf16; 1 ch/thread
__global__ void scan_apply(const ushort* __restrict__ xc, const ushort* __restrict__ zb,
                           const float* __restrict__ cw, const float* __restrict__ cb,
                           const float* __restrict__ Bm, const float* __restrict__ Cm,
                           const float* __restrict__ Dv, const float* __restrict__ offs,
                           ushort* __restrict__ v){
  int c = threadIdx.x;                    // 0..767
  int b = blockIdx.z, ch = blockIdx.x;
  int t0 = ch*CHUNK;
  size_t base = (size_t)b*NSEQ*768 + c;
  const ushort* xp = xc + base;
  const ushort* zp = zb + base;
  ushort* vp = v + base;
  float w0=cw[c*3+0], w1=cw[c*3+1], w2=cw[c*3+2], bia=cb[c];
  float bc=0.f;
  #pragma unroll
  for (int s=0;s<8;s++) bc += Bm[c*8+s]*Cm[c*8+s];
  float dd = Dv[c];
  float cu = offs[((size_t)b*NCHUNK + ch)*768 + c];
  float m2=0.f, m1=0.f;
  if (t0>=2) m2 = bf2f(xp[(size_t)(t0-2)*768]);
  if (t0>=1) m1 = bf2f(xp[(size_t)(t0-1)*768]);
  #pragma unroll 4
  for (int i=0;i<CHUNK;i++){
    size_t o = (size_t)(t0+i)*768;
    float x = bf2f(xp[o]);
    float z = bf2f(zp[o]);
    float u = silu_f(w0*m2 + w1*m1 + w2*x + bia);
    cu += u;
    float y = bc*cu + dd*u;
    vp[o] = f2bf(y * z);
    m2=m1; m1=x;
  }
}

extern "C" void kernel_launch(void* const* d_in, const int* in_sizes, int n_in,
                              void* d_out, int out_size, void* d_ws, size_t ws_size,
                              hipStream_t stream)
{
  const float* x      = (const float*)d_in[0];
  const float* W_in   = (const float*)d_in[1];
  const float* conv_w = (const float*)d_in[2];
  const float* conv_b = (const float*)d_in[3];
  const float* Bm     = (const float*)d_in[4];
  const float* Cm     = (const float*)d_in[5];
  const float* Dv     = (const float*)d_in[6];
  const float* W_out  = (const float*)d_in[7];
  float* out = (float*)d_out;

  char* ws = (char*)d_ws;
  ushort* xbf   = (ushort*)(ws + 0);          // 50331648; reused as v after GEMM1
  ushort* xcbf  = (ushort*)(ws + 50331648);   // 50331648
  ushort* zbf   = (ushort*)(ws + 100663296);  // 50331648
  ushort* wint  = (ushort*)(ws + 150994944);  // 2359296; dead after gemm1 -> offs aliases it
  ushort* woutt = (ushort*)(ws + 153354240);  // 1179648
  float*  psum  = (float*)(ws + 154533888);   // 1572864 (128 chunks x 768 x 4 batches)
  float*  offs  = (float*)(ws + 150994944);   // 1572864, aliases wint (written after gemm1 done)
  if (ws_size < 156106752) return;

  tr_cvt<<<dim3(1536/32, 768/32), 256, 0, stream>>>(W_in,  wint,  768, 1536);
  tr_cvt<<<dim3(768/32,  768/32), 256, 0, stream>>>(W_out, woutt, 768, 768);
  cvt_bf16<<<(MROWS*768)/2048, 256, 0, stream>>>(x, xbf, MROWS*768);

  gemm1_bt<<<dim3(MROWS/BM, 1536/BN), 256, 0, stream>>>(xbf, wint, xcbf, zbf, 768);

  conv_psum  <<<dim3(NCHUNK, 1, NBATCH), 768, 0, stream>>>(xcbf, conv_w, conv_b, psum);
  scan_chunks<<<12, 256, 0, stream>>>(psum, offs);
  scan_apply <<<dim3(NCHUNK, 1, NBATCH), 768, 0, stream>>>(xcbf, zbf, conv_w, conv_b,
                                                           Bm, Cm, Dv, offs, xbf /*v*/);

  gemm2_bt<<<dim3(MROWS/BM, 768/BN), 256, 0, stream>>>(xbf, woutt, out, 768);
}

// Round 7
// 385.802 us; speedup vs baseline: 1.0785x; 1.0132x over previous
//
#include <hip/hip_runtime.h>
#include <hip/hip_bf16.h>

#define D_MODEL 768
#define NSEQ    8192
#define NBATCH  4
#define MROWS   (NBATCH*NSEQ)   // 32768
#define CHUNK   64
#define NCHUNK  (NSEQ/CHUNK)    // 128

typedef __attribute__((ext_vector_type(8)))  short bshort8;
typedef __attribute__((ext_vector_type(4)))  float f32x4;

__device__ __forceinline__ float bf2f(ushort u){
  union { unsigned int i; float f; } x; x.i = ((unsigned int)u) << 16; return x.f;
}
__device__ __forceinline__ ushort f2bf(float f){
  union { float f; unsigned int i; } x; x.f = f;
  unsigned int r = x.i + 0x7fffu + ((x.i >> 16) & 1u);
  return (ushort)(r >> 16);
}
__device__ __forceinline__ float silu_f(float v){ return v / (1.0f + __expf(-v)); }

__device__ __forceinline__ void async_copy16(const ushort* g, ushort* l){
  __builtin_amdgcn_global_load_lds((const __attribute__((address_space(1))) void*)g,
                                   (__attribute__((address_space(3))) void*)l, 16, 0, 0);
}

// ---------------- weight transpose + bf16 convert: in[R][C] f32 -> out[C][R] bf16
__global__ void tr_cvt(const float* __restrict__ in, ushort* __restrict__ out, int R, int C){
  __shared__ float tile[32][33];
  int c0 = blockIdx.x*32, r0 = blockIdx.y*32;
  int tx = threadIdx.x & 31, ty = threadIdx.x >> 5;
  #pragma unroll
  for (int p=0;p<4;p++){
    int r = ty + p*8;
    tile[r][tx] = in[(size_t)(r0+r)*C + c0 + tx];
  }
  __syncthreads();
  #pragma unroll
  for (int p=0;p<4;p++){
    int c = ty + p*8;
    out[(size_t)(c0+c)*R + r0 + tx] = f2bf(tile[tx][c]);
  }
}

// ---------------- x fp32 -> bf16, 8 elems/thread, 16B stores
__global__ void cvt_bf16(const float* __restrict__ in, ushort* __restrict__ out, int n){
  int i = (blockIdx.x*256 + threadIdx.x)*8;
  if (i >= n) return;
  const float4 f0 = *(const float4*)(in + i);
  const float4 f1 = *(const float4*)(in + i + 4);
  ushort o[8];
  o[0]=f2bf(f0.x); o[1]=f2bf(f0.y); o[2]=f2bf(f0.z); o[3]=f2bf(f0.w);
  o[4]=f2bf(f1.x); o[5]=f2bf(f1.y); o[6]=f2bf(f1.z); o[7]=f2bf(f1.w);
  *(ulonglong2*)(out + i) = *(const ulonglong2*)o;
}

// =====================================================================
// Round-7 GEMM: 8-phase 256x256 pipelined template (T2+T3+T4+T5).
// Round-6 bug fixed: mmq_f accumulator indexing now accq[fm][nb+fn]
// (round-6's "accm0+fm" walked the flattened [8][4] array with stride 1,
// scrambling quadrants -> absmax 116).
// 8 waves (512 thr) 2M x 4N; per-wave 128x64 out; MFMA 16x16x32 bf16
// (16-row frags -> only 2-way bank alias under chunk^(r&7) swizzle).
// LDS 128KB: L[dbuf][mat][half][128*64]. Staging: global_load_lds with
// pre-swizzled source (slot p <-> row p>>3, chunk (p&7)^(r&7)); one
// half-tile (2 loads/thread) per phase into a region whose last reader
// completed >=1 barrier before the issue point. Counted vmcnt(2) at
// phase 3/7 ends only (never 0 in-loop). Phases 0-3 compute tile 2i
// from buf0, 4-7 tile 2i+1 from buf1. Stage map (iter i):
//  p0:Ah1(2i+1)->buf1  p1:Bh0(2i+1)->buf1  p2:Bh1(2i+1)->buf1
//  p3:Ah0(2i+2)->buf0  p4:Ah1(2i+2)->buf0  p5:Bh0(2i+2)->buf0
//  p6:Bh1(2i+2)->buf0  p7:Ah0(2i+3)->buf1
// Tails stage harmless duplicates (tile idx clamped to 0/1, dead or
// identical regions) so control flow and the vmcnt ledger stay uniform.
// Prologue stages tiles 0,1; vmcnt(8)+barrier. Final vmcnt(0) drains
// outstanding DMA before block exit (LDS reuse safety).
// =====================================================================

__device__ __forceinline__ void ldsA_f(const ushort* AHd, int mhofs, int rbase,
                                       const int cof0, const int cof1, bshort8 a[4][2]){
  #pragma unroll
  for (int fm=0; fm<4; ++fm){
    a[fm][0] = *(const bshort8*)(AHd + mhofs + fm*1024 + rbase + cof0);
    a[fm][1] = *(const bshort8*)(AHd + mhofs + fm*1024 + rbase + cof1);
  }
}
__device__ __forceinline__ void ldsB_f(const ushort* BP0, const ushort* BP1, int rbase,
                                       const int cof0, const int cof1, bshort8 b[2][2]){
  b[0][0] = *(const bshort8*)(BP0 + rbase + cof0);
  b[0][1] = *(const bshort8*)(BP0 + rbase + cof1);
  b[1][0] = *(const bshort8*)(BP1 + rbase + cof0);
  b[1][1] = *(const bshort8*)(BP1 + rbase + cof1);
}
// accq: pointer to 4 consecutive acc rows (quadrant); nb: column base (0 or 2)
__device__ __forceinline__ void mmq_f(const bshort8 a[4][2], const bshort8 b[2][2],
                                      f32x4 (*accq)[4], int nb){
  #pragma unroll
  for (int fm=0; fm<4; ++fm){
    #pragma unroll
    for (int fn=0; fn<2; ++fn){
      accq[fm][nb+fn] = __builtin_amdgcn_mfma_f32_16x16x32_bf16(a[fm][0], b[fn][0], accq[fm][nb+fn], 0,0,0);
      accq[fm][nb+fn] = __builtin_amdgcn_mfma_f32_16x16x32_bf16(a[fm][1], b[fn][1], accq[fm][nb+fn], 0,0,0);
    }
  }
}

#define PH_SYNC  do{ __builtin_amdgcn_sched_barrier(0); __builtin_amdgcn_s_barrier(); \
  asm volatile("s_waitcnt lgkmcnt(0)" ::: "memory"); __builtin_amdgcn_sched_barrier(0); \
  __builtin_amdgcn_s_setprio(1); }while(0)
#define PH_END   do{ __builtin_amdgcn_s_setprio(0); __builtin_amdgcn_sched_barrier(0); \
  __builtin_amdgcn_s_barrier(); }while(0)
#define PH_ENDV  do{ __builtin_amdgcn_s_setprio(0); __builtin_amdgcn_sched_barrier(0); \
  asm volatile("s_waitcnt vmcnt(2)" ::: "memory"); __builtin_amdgcn_s_barrier(); }while(0)

// MODE 1: dual bf16 out (xc | silu->z), N=1536, grid (128,6)
// MODE 2: f32 out, N=768, grid (128,3)
template<int MODE>
__global__ __launch_bounds__(512,2) void gemm8(
    const ushort* __restrict__ A, const ushort* __restrict__ BT,
    ushort* __restrict__ oxc, ushort* __restrict__ oz,
    float* __restrict__ of, int K)
{
  __shared__ __align__(16) ushort L[2][2][2][128*64];  // 128 KB
  const int tid  = threadIdx.x;
  const int bm   = blockIdx.x, bn = blockIdx.y;
  const int lane = tid & 63, wid = tid >> 6;
  const int wm   = wid >> 2;          // 0..1 -> A half / row block of 128
  const int wn   = wid & 3;           // 0..3 -> 64-col slice
  const int l15  = lane & 15, lh = lane >> 4;   // frag row lane / k-group

  // staging offsets (per thread): two 16B slots per phase
  const int p0i = tid, p1i = 512 + tid;
  const int r0s = p0i >> 3, c0s = (p0i & 7) ^ (r0s & 7);
  const int r1s = p1i >> 3, c1s = (p1i & 7) ^ (r1s & 7);
  const int ro0 = r0s*K + c0s*8, ro1 = r1s*K + c1s*8;
  const int so0 = p0i*8,         so1 = p1i*8;

  const ushort* Agb[2] = { A  + (size_t)(bm*256)*K, A  + (size_t)(bm*256 + 128)*K };
  const ushort* Bgb[2] = { BT + (size_t)(bn*256)*K, BT + (size_t)(bn*256 + 128)*K };

#define STGH(mat,h,t,d) do{ const ushort* _g = ((mat)? Bgb[h] : Agb[h]) + (t)*64; \
  ushort* _l = &L[d][mat][h][0]; \
  async_copy16(_g + ro0, _l + so0); async_copy16(_g + ro1, _l + so1); }while(0)

  // ds-read constants
  const int cof0 = ((0*4 + lh) ^ (l15 & 7)) * 8;   // ks=0 (k 0..31)
  const int cof1 = ((1*4 + lh) ^ (l15 & 7)) * 8;   // ks=1 (k 32..63)
  const int rbase = l15 * 64;
  const ushort* AH[2] = { &L[0][0][wm][0], &L[1][0][wm][0] };
  const ushort* BP[2][2][2];  // [dbuf][nh][fn]
  #pragma unroll
  for (int d=0; d<2; ++d)
    #pragma unroll
    for (int nh=0; nh<2; ++nh)
      #pragma unroll
      for (int fn=0; fn<2; ++fn){
        int off_n = wn*64 + nh*32 + fn*16;
        BP[d][nh][fn] = &L[d][1][off_n>>7][(off_n & 127)*64];
      }

  f32x4 acc[8][4];
  #pragma unroll
  for (int m=0;m<8;m++)
    #pragma unroll
    for (int n=0;n<4;n++)
      #pragma unroll
      for (int r=0;r<4;r++) acc[m][n][r] = 0.f;

  bshort8 a[4][2], b0[2][2], b1[2][2];

  // -------- prologue: tile 0 -> buf0, tile 1 -> buf1
  STGH(0,0,0,0); STGH(0,1,0,0); STGH(1,0,0,0); STGH(1,1,0,0);
  STGH(0,0,1,1); STGH(0,1,1,1); STGH(1,0,1,1); STGH(1,1,1,1);
  __builtin_amdgcn_sched_barrier(0);
  asm volatile("s_waitcnt vmcnt(8)" ::: "memory");   // tile 0 landed; tile 1 may fly
  __builtin_amdgcn_s_barrier();

  for (int i=0; i<6; ++i){
    const int t1 = 2*i + 1;                 // real (needed) for all i
    const int t2 = (i<5) ? 2*i + 2 : 0;     // dummy at i=5 (dead region, same parity)
    const int t3 = (i<5) ? 2*i + 3 : 1;     // dummy at i=5
    // ---- p0: A(mh0,buf0) + B(nh0,buf0); stage Ah1(t1)->buf1; MFMA q(0,0)
    ldsA_f(AH[0], 0,    rbase, cof0, cof1, a);
    ldsB_f(BP[0][0][0], BP[0][0][1], rbase, cof0, cof1, b0);
    STGH(0,1,t1,1);
    PH_SYNC; mmq_f(a, b0, &acc[0], 0); PH_END;
    // ---- p1: B(nh1,buf0); stage Bh0(t1)->buf1; MFMA q(0,1)
    ldsB_f(BP[0][1][0], BP[0][1][1], rbase, cof0, cof1, b1);
    STGH(1,0,t1,1);
    PH_SYNC; mmq_f(a, b1, &acc[0], 2); PH_END;
    // ---- p2: A(mh1,buf0); stage Bh1(t1)->buf1; MFMA q(1,0)
    ldsA_f(AH[0], 64*64, rbase, cof0, cof1, a);
    STGH(1,1,t1,1);
    PH_SYNC; mmq_f(a, b0, &acc[4], 0); PH_END;
    // ---- p3: stage Ah0(t2)->buf0; MFMA q(1,1); vmcnt(2) [tile 2i+1 landed]
    STGH(0,0,t2,0);
    PH_SYNC; mmq_f(a, b1, &acc[4], 2); PH_ENDV;
    // ---- p4: A(mh0,buf1) + B(nh0,buf1); stage Ah1(t2)->buf0; MFMA q(0,0)
    ldsA_f(AH[1], 0,    rbase, cof0, cof1, a);
    ldsB_f(BP[1][0][0], BP[1][0][1], rbase, cof0, cof1, b0);
    STGH(0,1,t2,0);
    PH_SYNC; mmq_f(a, b0, &acc[0], 0); PH_END;
    // ---- p5: B(nh1,buf1); stage Bh0(t2)->buf0; MFMA q(0,1)
    ldsB_f(BP[1][1][0], BP[1][1][1], rbase, cof0, cof1, b1);
    STGH(1,0,t2,0);
    PH_SYNC; mmq_f(a, b1, &acc[0], 2); PH_END;
    // ---- p6: A(mh1,buf1); stage Bh1(t2)->buf0; MFMA q(1,0)
    ldsA_f(AH[1], 64*64, rbase, cof0, cof1, a);
    STGH(1,1,t2,0);
    PH_SYNC; mmq_f(a, b0, &acc[4], 0); PH_END;
    // ---- p7: stage Ah0(t3)->buf1; MFMA q(1,1); vmcnt(2) [tile 2i+2 landed]
    STGH(0,0,t3,1);
    PH_SYNC; mmq_f(a, b1, &acc[4], 2); PH_ENDV;
  }
  asm volatile("s_waitcnt vmcnt(0)" ::: "memory");   // drain dummies before exit

  // -------- epilogue: C/D 16x16: col=lane&15, row=lh*4+reg
  #pragma unroll
  for (int m=0;m<8;m++){
    const int Rb = bm*256 + wm*128 + m*16 + lh*4;
    #pragma unroll
    for (int n=0;n<4;n++){
      const int Cc = bn*256 + wn*64 + n*16 + l15;
      #pragma unroll
      for (int r=0;r<4;r++){
        const float v = acc[m][n][r];
        const int R = Rb + r;
        if constexpr (MODE==1){
          if (bn < 3) oxc[(size_t)R*768 + Cc] = f2bf(v);
          else        oz [(size_t)R*768 + (Cc-768)] = f2bf(silu_f(v));
        } else {
          of[(size_t)R*768 + Cc] = v;
        }
      }
    }
  }
#undef STGH
}

// ---------------- pass 1: conv+silu, per-chunk sums (round-5 proven: 1 ch/thread)
__global__ void conv_psum(const ushort* __restrict__ xc, const float* __restrict__ cw,
                          const float* __restrict__ cb, float* __restrict__ psum){
  int c = threadIdx.x;                    // 0..767
  int b = blockIdx.z, ch = blockIdx.x;
  int t0 = ch*CHUNK;
  const ushort* xp = xc + (size_t)b*NSEQ*768 + c;
  float w0=cw[c*3+0], w1=cw[c*3+1], w2=cw[c*3+2], bia=cb[c];
  float m2=0.f, m1=0.f;
  if (t0>=2) m2 = bf2f(xp[(size_t)(t0-2)*768]);
  if (t0>=1) m1 = bf2f(xp[(size_t)(t0-1)*768]);
  float s=0.f;
  #pragma unroll 4
  for (int i=0;i<CHUNK;i++){
    float x = bf2f(xp[(size_t)(t0+i)*768]);
    s += silu_f(w0*m2 + w1*m1 + w2*x + bia);
    m2=m1; m1=x;
  }
  psum[((size_t)b*NCHUNK + ch)*768 + c] = s;
}

// ---------------- pass 2: exclusive scan of chunk sums per (b,c)
__global__ void scan_chunks(const float* __restrict__ psum, float* __restrict__ offs){
  int idx = blockIdx.x*256 + threadIdx.x; // 0..3071
  int b = idx/768, c = idx%768;
  float run = 0.f;
  #pragma unroll 8
  for (int ch=0; ch<NCHUNK; ch++){
    size_t o = ((size_t)b*NCHUNK + ch)*768 + c;
    offs[o] = run;
    run += psum[o];
  }
}

// ---------------- pass 3: replay conv+silu, apply SSM + gate -> v bf16; 1 ch/thread
__global__ void scan_apply(const ushort* __restrict__ xc, const ushort* __restrict__ zb,
                           const float* __restrict__ cw, const float* __restrict__ cb,
                           const float* __restrict__ Bm, const float* __restrict__ Cm,
                           const float* __restrict__ Dv, const float* __restrict__ offs,
                           ushort* __restrict__ v){
  int c = threadIdx.x;                    // 0..767
  int b = blockIdx.z, ch = blockIdx.x;
  int t0 = ch*CHUNK;
  size_t base = (size_t)b*NSEQ*768 + c;
  const ushort* xp = xc + base;
  const ushort* zp = zb + base;
  ushort* vp = v + base;
  float w0=cw[c*3+0], w1=cw[c*3+1], w2=cw[c*3+2], bia=cb[c];
  float bc=0.f;
  #pragma unroll
  for (int s=0;s<8;s++) bc += Bm[c*8+s]*Cm[c*8+s];
  float dd = Dv[c];
  float cu = offs[((size_t)b*NCHUNK + ch)*768 + c];
  float m2=0.f, m1=0.f;
  if (t0>=2) m2 = bf2f(xp[(size_t)(t0-2)*768]);
  if (t0>=1) m1 = bf2f(xp[(size_t)(t0-1)*768]);
  #pragma unroll 4
  for (int i=0;i<CHUNK;i++){
    size_t o = (size_t)(t0+i)*768;
    float x = bf2f(xp[o]);
    float z = bf2f(zp[o]);
    float u = silu_f(w0*m2 + w1*m1 + w2*x + bia);
    cu += u;
    float y = bc*cu + dd*u;
    vp[o] = f2bf(y * z);
    m2=m1; m1=x;
  }
}

extern "C" void kernel_launch(void* const* d_in, const int* in_sizes, int n_in,
                              void* d_out, int out_size, void* d_ws, size_t ws_size,
                              hipStream_t stream)
{
  const float* x      = (const float*)d_in[0];
  const float* W_in   = (const float*)d_in[1];
  const float* conv_w = (const float*)d_in[2];
  const float* conv_b = (const float*)d_in[3];
  const float* Bm     = (const float*)d_in[4];
  const float* Cm     = (const float*)d_in[5];
  const float* Dv     = (const float*)d_in[6];
  const float* W_out  = (const float*)d_in[7];
  float* out = (float*)d_out;

  char* ws = (char*)d_ws;
  ushort* xbf   = (ushort*)(ws + 0);          // 50331648; reused as v after GEMM1
  ushort* xcbf  = (ushort*)(ws + 50331648);   // 50331648
  ushort* zbf   = (ushort*)(ws + 100663296);  // 50331648
  ushort* wint  = (ushort*)(ws + 150994944);  // 2359296; dead after gemm1 -> offs aliases it
  ushort* woutt = (ushort*)(ws + 153354240);  // 1179648
  float*  psum  = (float*)(ws + 154533888);   // 1572864 (128 chunks x 768 x 4 batches)
  float*  offs  = (float*)(ws + 150994944);   // 1572864, aliases wint (written after gemm1 done)
  if (ws_size < 156106752) return;

  tr_cvt<<<dim3(1536/32, 768/32), 256, 0, stream>>>(W_in,  wint,  768, 1536);
  tr_cvt<<<dim3(768/32,  768/32), 256, 0, stream>>>(W_out, woutt, 768, 768);
  cvt_bf16<<<(MROWS*768)/2048, 256, 0, stream>>>(x, xbf, MROWS*768);

  gemm8<1><<<dim3(MROWS/256, 1536/256), 512, 0, stream>>>(xbf, wint, xcbf, zbf, nullptr, 768);

  conv_psum  <<<dim3(NCHUNK, 1, NBATCH), 768, 0, stream>>>(xcbf, conv_w, conv_b, psum);
  scan_chunks<<<12, 256, 0, stream>>>(psum, offs);
  scan_apply <<<dim3(NCHUNK, 1, NBATCH), 768, 0, stream>>>(xcbf, zbf, conv_w, conv_b,
                                                           Bm, Cm, Dv, offs, xbf /*v*/);

  gemm8<2><<<dim3(MROWS/256, 768/256), 512, 0, stream>>>(xbf, woutt, nullptr, nullptr, out, 768);
}